// Round 17
// baseline (455.318 us; speedup 1.0000x reference)
//
#include <hip/hip_runtime.h>
#include <math.h>

#define DIM 128
#define HEADS 8
#define HD 16
#define CAP 64

typedef __attribute__((ext_vector_type(8))) short s16x8;
typedef __attribute__((ext_vector_type(8))) unsigned short u16x8;
typedef __attribute__((ext_vector_type(4))) float f32x4;

__device__ __forceinline__ float lrelu(float x, float s) { return x >= 0.f ? x : s * x; }

__device__ __forceinline__ unsigned short f2bf(float x) {
  unsigned u = __float_as_uint(x);
  return (unsigned short)((u + 0x7FFFu + ((u >> 16) & 1u)) >> 16);
}
__device__ __forceinline__ float bf2f(unsigned short b) {
  return __uint_as_float(((unsigned)b) << 16);
}

// ---------------- CSR build ----------------
__global__ void k_hist(const int* __restrict__ ei, int E, int N, int* __restrict__ cnt) {
  int tot = E + N;
  for (int i = blockIdx.x * blockDim.x + threadIdx.x; i < tot; i += gridDim.x * blockDim.x) {
    int d = (i < E) ? ei[E + i] : (i - E);  // self-loops appended
    atomicAdd(&cnt[d], 1);
  }
}

__global__ __launch_bounds__(256) void k_scan_blk(const int* __restrict__ cnt, int n,
                                                  int* __restrict__ excl, int* __restrict__ bsum) {
  __shared__ int wsum[4];
  int tid = threadIdx.x, l = tid & 63, w = tid >> 6;
  int i = blockIdx.x * 256 + tid;
  int v = (i < n) ? cnt[i] : 0;
  int s = v;
#pragma unroll
  for (int off = 1; off < 64; off <<= 1) {
    int t = __shfl_up(s, off, 64);
    if (l >= off) s += t;
  }
  if (l == 63) wsum[w] = s;
  __syncthreads();
  int add = 0;
#pragma unroll
  for (int k = 0; k < 4; ++k) add += (k < w) ? wsum[k] : 0;
  if (i < n) excl[i] = s + add - v;
  if (tid == 255) bsum[blockIdx.x] = s + add;
}

__global__ __launch_bounds__(256) void k_scan_top(const int* __restrict__ bsum, int nb,
                                                  int* __restrict__ boff, int* __restrict__ rowptrN) {
  __shared__ int wsum[4];
  int tid = threadIdx.x, l = tid & 63, w = tid >> 6;
  int v = (tid < nb) ? bsum[tid] : 0;
  int s = v;
#pragma unroll
  for (int off = 1; off < 64; off <<= 1) {
    int t = __shfl_up(s, off, 64);
    if (l >= off) s += t;
  }
  if (l == 63) wsum[w] = s;
  __syncthreads();
  int add = 0;
#pragma unroll
  for (int k = 0; k < 4; ++k) add += (k < w) ? wsum[k] : 0;
  if (tid < nb) boff[tid] = s + add - v;
  if (tid == 255) *rowptrN = s + add;
}

__global__ __launch_bounds__(256) void k_scan_fix(int* __restrict__ cursor, const int* __restrict__ boff,
                                                  int n, int* __restrict__ rowptr) {
  int i = blockIdx.x * 256 + threadIdx.x;
  if (i < n) {
    int r = boff[blockIdx.x] + cursor[i];
    rowptr[i] = r;
    cursor[i] = r;
  }
}

// ---------------- unified weight prep + cnt zeroing ----------------
__global__ __launch_bounds__(256) void k_prep(
    const float* __restrict__ W1, const float* __restrict__ as1, const float* __restrict__ ad1,
    const float* __restrict__ W2, const float* __restrict__ as2, const float* __restrict__ ad2,
    const float* __restrict__ wm1,
    unsigned short* __restrict__ wh1,
    unsigned short* __restrict__ sh1, unsigned short* __restrict__ sl1,
    unsigned short* __restrict__ wh2,
    unsigned short* __restrict__ sh2, unsigned short* __restrict__ sl2,
    unsigned short* __restrict__ mh, unsigned short* __restrict__ ml,
    int* __restrict__ cnt, int N) {
  int b = blockIdx.x, tid = threadIdx.x;
  if (b < 32) {
    int layer = b >> 4;
    const float* W = layer ? W2 : W1;
    unsigned short* wh = layer ? wh2 : wh1;
    int lo = (b & 15) * 1024;
    for (int idx = lo + tid; idx < lo + 1024; idx += 256) {
      int n = idx >> 7, k = idx & 127;
      wh[idx] = f2bf(W[k * DIM + n]);
    }
  } else if (b < 36) {
    int layer = (b - 32) >> 1;
    const float* W = layer ? W2 : W1;
    const float* avs = layer ? as2 : as1;
    const float* avd = layer ? ad2 : ad1;
    unsigned short* sh = layer ? sh2 : sh1;
    unsigned short* sl = layer ? sl2 : sl1;
    int lo = ((b - 32) & 1) * 1024;
    for (int idx = lo + tid; idx < lo + 1024; idx += 256) {
      int n = idx >> 7, k = idx & 127;
      float acc = 0.f;
      if (n < 8) {
#pragma unroll
        for (int j = 0; j < 16; ++j) acc += W[k * DIM + n * 16 + j] * avs[n * 16 + j];
      } else {
        int h = n - 8;
#pragma unroll
        for (int j = 0; j < 16; ++j) acc += W[k * DIM + h * 16 + j] * avd[h * 16 + j];
      }
      unsigned short hb = f2bf(acc);
      sh[idx] = hb;
      sl[idx] = f2bf(acc - bf2f(hb));
    }
  } else if (b < 44) {
    int lo = (b - 36) * 1024;
    for (int idx = lo + tid; idx < lo + 1024; idx += 256) {
      int j = idx >> 7, k = idx & 127;   // mh[j][k] = wm1[k][j]
      float v = wm1[k * 64 + j];
      unsigned short hb = f2bf(v);
      mh[idx] = hb;
      ml[idx] = f2bf(v - bf2f(hb));
    }
  } else {
    int i0 = (b - 44) * 2048 + tid * 8;
    if (i0 + 8 <= N) {
      int4 z = {0, 0, 0, 0};
      *(int4*)(cnt + i0) = z;
      *(int4*)(cnt + i0 + 4) = z;
    } else {
      for (int i = i0; i < N; ++i) cnt[i] = 0;
    }
  }
}

// ---------------- linear (LDS-staged W, direct stores); optional fused scatter ----------------
template <int BF16IN, int FUSE>
__global__ __launch_bounds__(256) void k_linear_mfma(
    const void* __restrict__ xin,
    const unsigned short* __restrict__ wh,
    const unsigned short* __restrict__ sh, const unsigned short* __restrict__ sl,
    unsigned short* __restrict__ xhb, float* __restrict__ asrc, float* __restrict__ adst,
    int N, int GL,
    const int* __restrict__ ei, int E, int* __restrict__ cursor, int* __restrict__ colb) {
  if constexpr (FUSE == 1) {
    if ((int)blockIdx.x >= GL) {
      int tot = E + N;
      int nsb = gridDim.x - GL;
      for (int i = ((int)blockIdx.x - GL) * 256 + (int)threadIdx.x; i < tot; i += nsb * 256) {
        int s, d;
        if (i < E) { s = ei[i]; d = ei[E + i]; } else { s = i - E; d = s; }
        int pos = atomicAdd(&cursor[d], 1);
        colb[pos] = s;
      }
      return;
    }
  }
  __shared__ unsigned short sB[160][136];
  int tid = threadIdx.x, l = tid & 63, w = tid >> 6;
  int g = l >> 4, c = l & 15;
  int rb = blockIdx.x * 64;

  for (int i = tid; i < 160 * 16; i += 256) {
    int row = i >> 4, c8 = i & 15;
    u16x8 v;
    if (row < 128) v = *(const u16x8*)(wh + row * 128 + c8 * 8);
    else if (row < 144) v = *(const u16x8*)(sh + (row - 128) * 128 + c8 * 8);
    else v = *(const u16x8*)(sl + (row - 144) * 128 + c8 * 8);
    *(u16x8*)&sB[row][c8 * 8] = v;
  }

  int rc = min(rb + w * 16 + c, N - 1);
  s16x8 A[4];
  if constexpr (BF16IN) {
    const s16x8* xr = (const s16x8*)((const unsigned short*)xin + (size_t)rc * DIM);
#pragma unroll
    for (int kt = 0; kt < 4; ++kt) A[kt] = xr[kt * 4 + g];
  } else {
    const float4* xf = (const float4*)((const float*)xin + (size_t)rc * DIM);
#pragma unroll
    for (int kt = 0; kt < 4; ++kt) {
      float4 p = xf[kt * 8 + g * 2];
      float4 q = xf[kt * 8 + g * 2 + 1];
      s16x8 a;
      a[0] = (short)f2bf(p.x); a[1] = (short)f2bf(p.y);
      a[2] = (short)f2bf(p.z); a[3] = (short)f2bf(p.w);
      a[4] = (short)f2bf(q.x); a[5] = (short)f2bf(q.y);
      a[6] = (short)f2bf(q.z); a[7] = (short)f2bf(q.w);
      A[kt] = a;
    }
  }
  __syncthreads();

  f32x4 acc[8];
#pragma unroll
  for (int ct = 0; ct < 8; ++ct) acc[ct] = (f32x4){0.f, 0.f, 0.f, 0.f};
#pragma unroll
  for (int kt = 0; kt < 4; ++kt) {
    s16x8 a = A[kt];
#pragma unroll
    for (int ct = 0; ct < 8; ++ct) {
      s16x8 b = *(const s16x8*)&sB[ct * 16 + c][kt * 32 + g * 8];
      acc[ct] = __builtin_amdgcn_mfma_f32_16x16x32_bf16(a, b, acc[ct], 0, 0, 0);
    }
  }
  f32x4 accS = {0.f, 0.f, 0.f, 0.f};
#pragma unroll
  for (int kt = 0; kt < 4; ++kt) {
    s16x8 shi = *(const s16x8*)&sB[128 + c][kt * 32 + g * 8];
    s16x8 slo = *(const s16x8*)&sB[144 + c][kt * 32 + g * 8];
    accS = __builtin_amdgcn_mfma_f32_16x16x32_bf16(A[kt], shi, accS, 0, 0, 0);
    accS = __builtin_amdgcn_mfma_f32_16x16x32_bf16(A[kt], slo, accS, 0, 0, 0);
  }

  // direct stores (32B contiguous per 16-lane group)
#pragma unroll
  for (int r = 0; r < 4; ++r) {
    int rr = rb + w * 16 + g * 4 + r;
    if (rr < N) {
#pragma unroll
      for (int ct = 0; ct < 8; ++ct)
        xhb[(size_t)rr * DIM + ct * 16 + c] = f2bf(acc[ct][r]);
      if (c < 8) asrc[rr * HEADS + c] = accS[r];
      else adst[rr * HEADS + (c - 8)] = accS[r];
    }
  }
}

// ---------------- GAT aggregation: head-sliced, XCD-affine ----------------
// Block b: head s = b&7 (XCD-affine via round-robin dispatch), nodes [(b>>3)*16, +16).
// Per-XCD working set = xhb column slice (1.6MB) + asrc column -> L2-resident.
// Wave = 4 nodes sequentially; lanes: e=lane>>4 edge slot, d=lane&15 dim within head.
__global__ __launch_bounds__(256) void k_gat_agg(const int* __restrict__ rowptr, const int* __restrict__ colb,
                                                 const unsigned short* __restrict__ xhb,
                                                 const float* __restrict__ asrc, const float* __restrict__ adst,
                                                 const float* __restrict__ bias,
                                                 unsigned short* __restrict__ houtb, int N) {
  __shared__ int ci[4][CAP];
  int tid = threadIdx.x, lane = tid & 63, wv = tid >> 6;
  int s = blockIdx.x & 7;
  int n0 = (blockIdx.x >> 3) * 16 + wv * 4;
  int e = lane >> 4, d = lane & 15;
  float bv = bias[s * HD + d];

#pragma unroll
  for (int k = 0; k < 4; ++k) {
    int n = n0 + k;
    if (n >= N) break;
    int base = rowptr[n];
    int deg = rowptr[n + 1] - base;
    if (lane < deg && lane < CAP) ci[wv][lane] = colb[base + lane];
    // wave-private LDS: in-wave ordering handled by compiler waitcnt; no barrier needed
    float adn = adst[n * HEADS + s];
    float den = 0.f, acc = 0.f;
#define EDGE(ii) { \
      int c_ = ((ii) < CAP) ? ci[wv][(ii)] : colb[base + (ii)]; \
      float e_ = lrelu(asrc[c_ * HEADS + s] + adn, 0.2f); \
      float w_ = __expf(e_); \
      den += w_; \
      acc = fmaf(w_, bf2f(xhb[(size_t)c_ * DIM + s * HD + d]), acc); }
    int i = e;
    for (; i + 4 < deg; i += 8) { EDGE(i); EDGE(i + 4); }
    for (; i < deg; i += 4) { EDGE(i); }
#undef EDGE
    den += __shfl_xor(den, 16, 64);
    den += __shfl_xor(den, 32, 64);
    acc += __shfl_xor(acc, 16, 64);
    acc += __shfl_xor(acc, 32, 64);
    if (e == 0) {
      float r = 1.f / (den + 1e-16f);
      houtb[(size_t)n * DIM + s * HD + d] = f2bf(lrelu(fmaf(acc, r, bv), 0.01f));
    }
  }
}

// ---------------- fused score MLP + softmax pooling: per-block partials ----------------
__global__ __launch_bounds__(256) void k_score_pool(
    const unsigned short* __restrict__ h2b,
    const unsigned short* __restrict__ mh, const unsigned short* __restrict__ ml,
    const float* __restrict__ bm1, const float* __restrict__ wm2, const float* __restrict__ bm2,
    float* __restrict__ pagg, float* __restrict__ psum, int N) {
  __shared__ float se[4][16];
  __shared__ float blkacc[4][128];
  __shared__ float swave[4];
  int tid = threadIdx.x, l = tid & 63, w = tid >> 6;
  int g = l >> 4, c = l & 15;
  int rbase = blockIdx.x * 64 + w * 16;
  int rc = min(rbase + c, N - 1);
  const s16x8* xr = (const s16x8*)(h2b + (size_t)rc * DIM);
  s16x8 A[4];
#pragma unroll
  for (int kt = 0; kt < 4; ++kt) A[kt] = xr[kt * 4 + g];

  const s16x8* Bh = (const s16x8*)mh;
  const s16x8* Bl = (const s16x8*)ml;
  float v[4] = {0.f, 0.f, 0.f, 0.f};
#pragma unroll
  for (int ct = 0; ct < 4; ++ct) {
    f32x4 acc = {0.f, 0.f, 0.f, 0.f};
#pragma unroll
    for (int kt = 0; kt < 4; ++kt) {
      s16x8 bh = Bh[(ct * 16 + c) * 16 + kt * 4 + g];
      s16x8 bl = Bl[(ct * 16 + c) * 16 + kt * 4 + g];
      acc = __builtin_amdgcn_mfma_f32_16x16x32_bf16(A[kt], bh, acc, 0, 0, 0);
      acc = __builtin_amdgcn_mfma_f32_16x16x32_bf16(A[kt], bl, acc, 0, 0, 0);
    }
    int col = ct * 16 + c;
    float b = bm1[col], w2 = wm2[col];
#pragma unroll
    for (int r = 0; r < 4; ++r) v[r] += lrelu(acc[r] + b, 0.01f) * w2;
  }
#pragma unroll
  for (int r = 0; r < 4; ++r) {
    v[r] += __shfl_xor(v[r], 1, 64);
    v[r] += __shfl_xor(v[r], 2, 64);
    v[r] += __shfl_xor(v[r], 4, 64);
    v[r] += __shfl_xor(v[r], 8, 64);
  }
  float b2 = bm2[0];
  float e[4];
#pragma unroll
  for (int r = 0; r < 4; ++r) {
    int rr = rbase + g * 4 + r;
    e[r] = (rr < N) ? __expf(v[r] + b2) : 0.f;
  }
  if (c == 0) {
#pragma unroll
    for (int r = 0; r < 4; ++r) se[w][g * 4 + r] = e[r];
  }
  __syncthreads();
  float emy = se[w][c];   // e for this lane's row (rbase+c)
  float pa[32];
#pragma unroll
  for (int kt = 0; kt < 4; ++kt)
#pragma unroll
    for (int j = 0; j < 8; ++j)
      pa[kt * 8 + j] = emy * bf2f((unsigned short)A[kt][j]);
#pragma unroll
  for (int k = 0; k < 32; ++k) {
    pa[k] += __shfl_xor(pa[k], 1, 64);
    pa[k] += __shfl_xor(pa[k], 2, 64);
    pa[k] += __shfl_xor(pa[k], 4, 64);
    pa[k] += __shfl_xor(pa[k], 8, 64);
  }
  if (c == 0) {
#pragma unroll
    for (int kt = 0; kt < 4; ++kt)
#pragma unroll
      for (int j = 0; j < 8; ++j)
        blkacc[w][kt * 32 + g * 8 + j] = pa[kt * 8 + j];
  }
  float ws = e[0] + e[1] + e[2] + e[3];
  ws += __shfl_xor(ws, 16, 64);
  ws += __shfl_xor(ws, 32, 64);
  if (l == 0) swave[w] = ws;
  __syncthreads();
  if (tid < 128) {
    float s = blkacc[0][tid] + blkacc[1][tid] + blkacc[2][tid] + blkacc[3][tid];
    pagg[(size_t)blockIdx.x * DIM + tid] = s;
  }
  if (tid == 0) psum[blockIdx.x] = swave[0] + swave[1] + swave[2] + swave[3];
}

// ---------------- final: parallel partial-reduce + MLP + layernorm (1024 threads) ----------------
__global__ __launch_bounds__(1024) void k_final(const float* __restrict__ psum, const float* __restrict__ pagg,
                                                int nb,
                                                const float* __restrict__ wa1, const float* __restrict__ ba1,
                                                const float* __restrict__ wa2, const float* __restrict__ ba2,
                                                const float* __restrict__ gamma, const float* __restrict__ beta,
                                                float* __restrict__ out) {
  __shared__ float redz[1024];
  __shared__ float reda[8][128];
  __shared__ float sa[128], shh[64], red[128];
  int t = threadIdx.x;
  float zp = 0.f;
  for (int b = t; b < nb; b += 1024) zp += psum[b];
  redz[t] = zp;
  __syncthreads();
  for (int st = 512; st > 0; st >>= 1) { if (t < st) redz[t] += redz[t + st]; __syncthreads(); }
  int d = t & 127, g = t >> 7;
  float ag = 0.f;
  for (int b = g; b < nb; b += 8) ag += pagg[(size_t)b * DIM + d];
  reda[g][d] = ag;
  __syncthreads();
  if (g == 0) {
    float s = 0.f;
#pragma unroll
    for (int k = 0; k < 8; ++k) s += reda[k][d];
    sa[d] = s / redz[0];
  }
  __syncthreads();
  if (t < 64) {
    float a = 0.f;
    for (int k = 0; k < 128; ++k) a = fmaf(sa[k], wa1[k * 64 + t], a);
    a += ba1[t];
    shh[t] = lrelu(a, 0.01f);
  }
  __syncthreads();
  float zval = 0.f;
  if (t < 128) {
    zval = ba2[t];
    for (int j = 0; j < 64; ++j) zval = fmaf(shh[j], wa2[j * 128 + t], zval);
    red[t] = zval;
  }
  __syncthreads();
  for (int st = 64; st > 0; st >>= 1) { if (t < st) red[t] += red[t + st]; __syncthreads(); }
  float mu = red[0] / 128.f;
  __syncthreads();
  if (t < 128) red[t] = (zval - mu) * (zval - mu);
  __syncthreads();
  for (int st = 64; st > 0; st >>= 1) { if (t < st) red[t] += red[t + st]; __syncthreads(); }
  float var = red[0] / 128.f;
  if (t < 128) out[t] = gamma[t] * (zval - mu) / sqrtf(var + 1e-5f) + beta[t];
}

extern "C" void kernel_launch(void* const* d_in, const int* in_sizes, int n_in,
                              void* d_out, int out_size, void* d_ws, size_t ws_size,
                              hipStream_t stream) {
  const float* feat = (const float*)d_in[0];
  const int* ei = (const int*)d_in[1];
  const float* W1 = (const float*)d_in[2];
  const float* as1 = (const float*)d_in[3];
  const float* ad1 = (const float*)d_in[4];
  const float* b1 = (const float*)d_in[5];
  const float* W2 = (const float*)d_in[6];
  const float* as2 = (const float*)d_in[7];
  const float* ad2 = (const float*)d_in[8];
  const float* b2 = (const float*)d_in[9];
  const float* wm1 = (const float*)d_in[10];
  const float* bm1 = (const float*)d_in[11];
  const float* wm2 = (const float*)d_in[12];
  const float* bm2 = (const float*)d_in[13];
  const float* wa1 = (const float*)d_in[14];
  const float* ba1 = (const float*)d_in[15];
  const float* wa2 = (const float*)d_in[16];
  const float* ba2 = (const float*)d_in[17];
  const float* gamma = (const float*)d_in[18];
  const float* beta = (const float*)d_in[19];
  float* out = (float*)d_out;

  int N = in_sizes[0] / DIM;   // 50000
  int E = in_sizes[1] / 2;     // 600000
  int NB = (N + 255) / 256;
  int ZB = (N + 2047) / 2048;
  int GL = (N + 63) / 64;      // linear blocks (64 rows each)
  int GS = 448;                // scatter blocks in fused kernel
  int gs = (N + 63) / 64;      // score_pool blocks
  int ga = ((N + 15) / 16) * 8;  // gat blocks: head-sliced

  char* ws = (char*)d_ws;
  size_t off = 0;
  auto alloc = [&](size_t bytes) -> void* {
    void* p = ws + off;
    off = (off + bytes + 255) & ~(size_t)255;
    return p;
  };
  int* cnt = (int*)alloc((size_t)N * 4);
  int* rowptr = (int*)alloc((size_t)(N + 1) * 4);
  int* cursor = (int*)alloc((size_t)N * 4);
  int* colb = (int*)alloc((size_t)(E + N) * 4);
  unsigned short* xhb = (unsigned short*)alloc((size_t)N * DIM * 2);
  unsigned short* h1b = (unsigned short*)alloc((size_t)N * DIM * 2);
  unsigned short* h2b = (unsigned short*)alloc((size_t)N * DIM * 2);
  float* asrcb = (float*)alloc((size_t)N * HEADS * 4);
  float* adstb = (float*)alloc((size_t)N * HEADS * 4);
  float* pagg = (float*)alloc((size_t)gs * DIM * 4);
  float* psum = (float*)alloc((size_t)gs * 4);
  int* bsum = (int*)alloc((size_t)NB * 4);
  int* boff = (int*)alloc((size_t)NB * 4);
  unsigned short* wh1 = (unsigned short*)alloc(DIM * DIM * 2);
  unsigned short* sh1 = (unsigned short*)alloc(16 * DIM * 2);
  unsigned short* sl1 = (unsigned short*)alloc(16 * DIM * 2);
  unsigned short* wh2 = (unsigned short*)alloc(DIM * DIM * 2);
  unsigned short* sh2 = (unsigned short*)alloc(16 * DIM * 2);
  unsigned short* sl2 = (unsigned short*)alloc(16 * DIM * 2);
  unsigned short* mh = (unsigned short*)alloc(64 * DIM * 2);
  unsigned short* ml = (unsigned short*)alloc(64 * DIM * 2);

  k_prep<<<44 + ZB, 256, 0, stream>>>(W1, as1, ad1, W2, as2, ad2, wm1,
                                      wh1, sh1, sl1, wh2, sh2, sl2, mh, ml, cnt, N);

  k_hist<<<1024, 256, 0, stream>>>(ei, E, N, cnt);
  k_scan_blk<<<NB, 256, 0, stream>>>(cnt, N, cursor, bsum);
  k_scan_top<<<1, 256, 0, stream>>>(bsum, NB, boff, rowptr + N);
  k_scan_fix<<<NB, 256, 0, stream>>>(cursor, boff, N, rowptr);

  // fused: layer-1 linear (blocks < GL) + CSR edge scatter (blocks >= GL)
  k_linear_mfma<0, 1><<<GL + GS, 256, 0, stream>>>(feat, wh1, sh1, sl1, xhb, asrcb, adstb,
                                                   N, GL, ei, E, cursor, colb);

  k_gat_agg<<<ga, 256, 0, stream>>>(rowptr, colb, xhb, asrcb, adstb, b1, h1b, N);
  k_linear_mfma<1, 0><<<GL, 256, 0, stream>>>(h1b, wh2, sh2, sl2, xhb, asrcb, adstb,
                                              N, GL, nullptr, 0, nullptr, nullptr);
  k_gat_agg<<<ga, 256, 0, stream>>>(rowptr, colb, xhb, asrcb, adstb, b2, h2b, N);

  k_score_pool<<<gs, 256, 0, stream>>>(h2b, mh, ml, bm1, wm2, bm2, pagg, psum, N);
  k_final<<<1, 1024, 0, stream>>>(psum, pagg, gs, wa1, ba1, wa2, ba2, gamma, beta, out);
}

// Round 18
// 229.224 us; speedup vs baseline: 1.9863x; 1.9863x over previous
//
#include <hip/hip_runtime.h>
#include <math.h>

#define DIM 128
#define HEADS 8
#define HD 16
#define CAP 64

typedef __attribute__((ext_vector_type(8))) short s16x8;
typedef __attribute__((ext_vector_type(8))) unsigned short u16x8;
typedef __attribute__((ext_vector_type(4))) float f32x4;

__device__ __forceinline__ float lrelu(float x, float s) { return x >= 0.f ? x : s * x; }

__device__ __forceinline__ unsigned short f2bf(float x) {
  unsigned u = __float_as_uint(x);
  return (unsigned short)((u + 0x7FFFu + ((u >> 16) & 1u)) >> 16);
}
__device__ __forceinline__ float bf2f(unsigned short b) {
  return __uint_as_float(((unsigned)b) << 16);
}

// ---------------- CSR build ----------------
__global__ void k_hist(const int* __restrict__ ei, int E, int N, int* __restrict__ cnt) {
  int tot = E + N;
  for (int i = blockIdx.x * blockDim.x + threadIdx.x; i < tot; i += gridDim.x * blockDim.x) {
    int d = (i < E) ? ei[E + i] : (i - E);  // self-loops appended
    atomicAdd(&cnt[d], 1);
  }
}

__global__ __launch_bounds__(256) void k_scan_blk(const int* __restrict__ cnt, int n,
                                                  int* __restrict__ excl, int* __restrict__ bsum) {
  __shared__ int wsum[4];
  int tid = threadIdx.x, l = tid & 63, w = tid >> 6;
  int i = blockIdx.x * 256 + tid;
  int v = (i < n) ? cnt[i] : 0;
  int s = v;
#pragma unroll
  for (int off = 1; off < 64; off <<= 1) {
    int t = __shfl_up(s, off, 64);
    if (l >= off) s += t;
  }
  if (l == 63) wsum[w] = s;
  __syncthreads();
  int add = 0;
#pragma unroll
  for (int k = 0; k < 4; ++k) add += (k < w) ? wsum[k] : 0;
  if (i < n) excl[i] = s + add - v;
  if (tid == 255) bsum[blockIdx.x] = s + add;
}

__global__ __launch_bounds__(256) void k_scan_top(const int* __restrict__ bsum, int nb,
                                                  int* __restrict__ boff, int* __restrict__ rowptrN) {
  __shared__ int wsum[4];
  int tid = threadIdx.x, l = tid & 63, w = tid >> 6;
  int v = (tid < nb) ? bsum[tid] : 0;
  int s = v;
#pragma unroll
  for (int off = 1; off < 64; off <<= 1) {
    int t = __shfl_up(s, off, 64);
    if (l >= off) s += t;
  }
  if (l == 63) wsum[w] = s;
  __syncthreads();
  int add = 0;
#pragma unroll
  for (int k = 0; k < 4; ++k) add += (k < w) ? wsum[k] : 0;
  if (tid < nb) boff[tid] = s + add - v;
  if (tid == 255) *rowptrN = s + add;
}

__global__ __launch_bounds__(256) void k_scan_fix(int* __restrict__ cursor, const int* __restrict__ boff,
                                                  int n, int* __restrict__ rowptr) {
  int i = blockIdx.x * 256 + threadIdx.x;
  if (i < n) {
    int r = boff[blockIdx.x] + cursor[i];
    rowptr[i] = r;
    cursor[i] = r;
  }
}

// ---------------- unified weight prep + cnt zeroing ----------------
__global__ __launch_bounds__(256) void k_prep(
    const float* __restrict__ W1, const float* __restrict__ as1, const float* __restrict__ ad1,
    const float* __restrict__ W2, const float* __restrict__ as2, const float* __restrict__ ad2,
    const float* __restrict__ wm1,
    unsigned short* __restrict__ wh1,
    unsigned short* __restrict__ sh1, unsigned short* __restrict__ sl1,
    unsigned short* __restrict__ wh2,
    unsigned short* __restrict__ sh2, unsigned short* __restrict__ sl2,
    unsigned short* __restrict__ mh, unsigned short* __restrict__ ml,
    int* __restrict__ cnt, int N) {
  int b = blockIdx.x, tid = threadIdx.x;
  if (b < 32) {
    int layer = b >> 4;
    const float* W = layer ? W2 : W1;
    unsigned short* wh = layer ? wh2 : wh1;
    int lo = (b & 15) * 1024;
    for (int idx = lo + tid; idx < lo + 1024; idx += 256) {
      int n = idx >> 7, k = idx & 127;
      wh[idx] = f2bf(W[k * DIM + n]);
    }
  } else if (b < 36) {
    int layer = (b - 32) >> 1;
    const float* W = layer ? W2 : W1;
    const float* avs = layer ? as2 : as1;
    const float* avd = layer ? ad2 : ad1;
    unsigned short* sh = layer ? sh2 : sh1;
    unsigned short* sl = layer ? sl2 : sl1;
    int lo = ((b - 32) & 1) * 1024;
    for (int idx = lo + tid; idx < lo + 1024; idx += 256) {
      int n = idx >> 7, k = idx & 127;
      float acc = 0.f;
      if (n < 8) {
#pragma unroll
        for (int j = 0; j < 16; ++j) acc += W[k * DIM + n * 16 + j] * avs[n * 16 + j];
      } else {
        int h = n - 8;
#pragma unroll
        for (int j = 0; j < 16; ++j) acc += W[k * DIM + h * 16 + j] * avd[h * 16 + j];
      }
      unsigned short hb = f2bf(acc);
      sh[idx] = hb;
      sl[idx] = f2bf(acc - bf2f(hb));
    }
  } else if (b < 44) {
    int lo = (b - 36) * 1024;
    for (int idx = lo + tid; idx < lo + 1024; idx += 256) {
      int j = idx >> 7, k = idx & 127;   // mh[j][k] = wm1[k][j]
      float v = wm1[k * 64 + j];
      unsigned short hb = f2bf(v);
      mh[idx] = hb;
      ml[idx] = f2bf(v - bf2f(hb));
    }
  } else {
    int i0 = (b - 44) * 2048 + tid * 8;
    if (i0 + 8 <= N) {
      int4 z = {0, 0, 0, 0};
      *(int4*)(cnt + i0) = z;
      *(int4*)(cnt + i0 + 4) = z;
    } else {
      for (int i = i0; i < N; ++i) cnt[i] = 0;
    }
  }
}

// ---------------- linear (LDS-staged W, direct stores); optional fused scatter ----------------
template <int BF16IN, int FUSE>
__global__ __launch_bounds__(256) void k_linear_mfma(
    const void* __restrict__ xin,
    const unsigned short* __restrict__ wh,
    const unsigned short* __restrict__ sh, const unsigned short* __restrict__ sl,
    unsigned short* __restrict__ xhb, float* __restrict__ asrc, float* __restrict__ adst,
    int N, int GL,
    const int* __restrict__ ei, int E, int* __restrict__ cursor, int* __restrict__ colb) {
  if constexpr (FUSE == 1) {
    if ((int)blockIdx.x >= GL) {
      int tot = E + N;
      int nsb = gridDim.x - GL;
      for (int i = ((int)blockIdx.x - GL) * 256 + (int)threadIdx.x; i < tot; i += nsb * 256) {
        int s, d;
        if (i < E) { s = ei[i]; d = ei[E + i]; } else { s = i - E; d = s; }
        int pos = atomicAdd(&cursor[d], 1);
        colb[pos] = s;
      }
      return;
    }
  }
  __shared__ unsigned short sB[160][136];
  int tid = threadIdx.x, l = tid & 63, w = tid >> 6;
  int g = l >> 4, c = l & 15;
  int rb = blockIdx.x * 64;

  for (int i = tid; i < 160 * 16; i += 256) {
    int row = i >> 4, c8 = i & 15;
    u16x8 v;
    if (row < 128) v = *(const u16x8*)(wh + row * 128 + c8 * 8);
    else if (row < 144) v = *(const u16x8*)(sh + (row - 128) * 128 + c8 * 8);
    else v = *(const u16x8*)(sl + (row - 144) * 128 + c8 * 8);
    *(u16x8*)&sB[row][c8 * 8] = v;
  }

  int rc = min(rb + w * 16 + c, N - 1);
  s16x8 A[4];
  if constexpr (BF16IN) {
    const s16x8* xr = (const s16x8*)((const unsigned short*)xin + (size_t)rc * DIM);
#pragma unroll
    for (int kt = 0; kt < 4; ++kt) A[kt] = xr[kt * 4 + g];
  } else {
    const float4* xf = (const float4*)((const float*)xin + (size_t)rc * DIM);
#pragma unroll
    for (int kt = 0; kt < 4; ++kt) {
      float4 p = xf[kt * 8 + g * 2];
      float4 q = xf[kt * 8 + g * 2 + 1];
      s16x8 a;
      a[0] = (short)f2bf(p.x); a[1] = (short)f2bf(p.y);
      a[2] = (short)f2bf(p.z); a[3] = (short)f2bf(p.w);
      a[4] = (short)f2bf(q.x); a[5] = (short)f2bf(q.y);
      a[6] = (short)f2bf(q.z); a[7] = (short)f2bf(q.w);
      A[kt] = a;
    }
  }
  __syncthreads();

  f32x4 acc[8];
#pragma unroll
  for (int ct = 0; ct < 8; ++ct) acc[ct] = (f32x4){0.f, 0.f, 0.f, 0.f};
#pragma unroll
  for (int kt = 0; kt < 4; ++kt) {
    s16x8 a = A[kt];
#pragma unroll
    for (int ct = 0; ct < 8; ++ct) {
      s16x8 b = *(const s16x8*)&sB[ct * 16 + c][kt * 32 + g * 8];
      acc[ct] = __builtin_amdgcn_mfma_f32_16x16x32_bf16(a, b, acc[ct], 0, 0, 0);
    }
  }
  f32x4 accS = {0.f, 0.f, 0.f, 0.f};
#pragma unroll
  for (int kt = 0; kt < 4; ++kt) {
    s16x8 shi = *(const s16x8*)&sB[128 + c][kt * 32 + g * 8];
    s16x8 slo = *(const s16x8*)&sB[144 + c][kt * 32 + g * 8];
    accS = __builtin_amdgcn_mfma_f32_16x16x32_bf16(A[kt], shi, accS, 0, 0, 0);
    accS = __builtin_amdgcn_mfma_f32_16x16x32_bf16(A[kt], slo, accS, 0, 0, 0);
  }

  // direct stores (32B contiguous per 16-lane group)
#pragma unroll
  for (int r = 0; r < 4; ++r) {
    int rr = rb + w * 16 + g * 4 + r;
    if (rr < N) {
#pragma unroll
      for (int ct = 0; ct < 8; ++ct)
        xhb[(size_t)rr * DIM + ct * 16 + c] = f2bf(acc[ct][r]);
      if (c < 8) asrc[rr * HEADS + c] = accS[r];
      else adst[rr * HEADS + (c - 8)] = accS[r];
    }
  }
}

// ---------------- GAT aggregation: full-row per wave, single-pass softmax (R16 known-good) ----
__global__ __launch_bounds__(256) void k_gat_agg(const int* __restrict__ rowptr, const int* __restrict__ colb,
                                                 const unsigned short* __restrict__ xhb,
                                                 const float* __restrict__ asrc, const float* __restrict__ adst,
                                                 const float* __restrict__ bias,
                                                 unsigned short* __restrict__ houtb, int N) {
  __shared__ int ci[4][CAP];
  int tid = threadIdx.x, lane = tid & 63, wv = tid >> 6;
  int n = blockIdx.x * 4 + wv;
  int base = 0, deg = 0;
  if (n < N) { base = rowptr[n]; deg = rowptr[n + 1] - base; }
  if (lane < deg && lane < CAP) ci[wv][lane] = colb[base + lane];
  __syncthreads();
  if (n >= N) return;

  int qt = lane >> 4, q = lane & 15;   // quarter = edge slot parity; lane covers dims [8q, 8q+8)
  int h = q >> 1;
  float adn = adst[n * HEADS + h];
  float den = 0.f;
  float a0 = 0.f, a1 = 0.f, a2 = 0.f, a3 = 0.f, a4 = 0.f, a5 = 0.f, a6 = 0.f, a7 = 0.f;
#define EDGE(ii) { \
    int c_ = ((ii) < CAP) ? ci[wv][(ii)] : colb[base + (ii)]; \
    float e_ = lrelu(asrc[c_ * HEADS + h] + adn, 0.2f); \
    float w_ = __expf(e_); \
    den += w_; \
    u16x8 u_ = *(const u16x8*)(xhb + (size_t)c_ * DIM + q * 8); \
    a0 = fmaf(w_, bf2f((unsigned short)u_[0]), a0); \
    a1 = fmaf(w_, bf2f((unsigned short)u_[1]), a1); \
    a2 = fmaf(w_, bf2f((unsigned short)u_[2]), a2); \
    a3 = fmaf(w_, bf2f((unsigned short)u_[3]), a3); \
    a4 = fmaf(w_, bf2f((unsigned short)u_[4]), a4); \
    a5 = fmaf(w_, bf2f((unsigned short)u_[5]), a5); \
    a6 = fmaf(w_, bf2f((unsigned short)u_[6]), a6); \
    a7 = fmaf(w_, bf2f((unsigned short)u_[7]), a7); }
  int i = qt;
  for (; i + 4 < deg; i += 8) { EDGE(i); EDGE(i + 4); }
  for (; i < deg; i += 4) { EDGE(i); }
#undef EDGE
  den += __shfl_xor(den, 16, 64); den += __shfl_xor(den, 32, 64);
  a0 += __shfl_xor(a0, 16, 64); a0 += __shfl_xor(a0, 32, 64);
  a1 += __shfl_xor(a1, 16, 64); a1 += __shfl_xor(a1, 32, 64);
  a2 += __shfl_xor(a2, 16, 64); a2 += __shfl_xor(a2, 32, 64);
  a3 += __shfl_xor(a3, 16, 64); a3 += __shfl_xor(a3, 32, 64);
  a4 += __shfl_xor(a4, 16, 64); a4 += __shfl_xor(a4, 32, 64);
  a5 += __shfl_xor(a5, 16, 64); a5 += __shfl_xor(a5, 32, 64);
  a6 += __shfl_xor(a6, 16, 64); a6 += __shfl_xor(a6, 32, 64);
  a7 += __shfl_xor(a7, 16, 64); a7 += __shfl_xor(a7, 32, 64);
  if (qt == 0) {
    float r = 1.f / (den + 1e-16f);
    const float4* bp = (const float4*)(bias + q * 8);
    float4 b0 = bp[0], b1 = bp[1];
    u16x8 o;
    o[0] = f2bf(lrelu(fmaf(a0, r, b0.x), 0.01f));
    o[1] = f2bf(lrelu(fmaf(a1, r, b0.y), 0.01f));
    o[2] = f2bf(lrelu(fmaf(a2, r, b0.z), 0.01f));
    o[3] = f2bf(lrelu(fmaf(a3, r, b0.w), 0.01f));
    o[4] = f2bf(lrelu(fmaf(a4, r, b1.x), 0.01f));
    o[5] = f2bf(lrelu(fmaf(a5, r, b1.y), 0.01f));
    o[6] = f2bf(lrelu(fmaf(a6, r, b1.z), 0.01f));
    o[7] = f2bf(lrelu(fmaf(a7, r, b1.w), 0.01f));
    *(u16x8*)(houtb + (size_t)n * DIM + q * 8) = o;
  }
}

// ---------------- fused score MLP + softmax pooling: per-block partials ----------------
__global__ __launch_bounds__(256) void k_score_pool(
    const unsigned short* __restrict__ h2b,
    const unsigned short* __restrict__ mh, const unsigned short* __restrict__ ml,
    const float* __restrict__ bm1, const float* __restrict__ wm2, const float* __restrict__ bm2,
    float* __restrict__ pagg, float* __restrict__ psum, int N) {
  __shared__ float se[4][16];
  __shared__ float blkacc[4][128];
  __shared__ float swave[4];
  int tid = threadIdx.x, l = tid & 63, w = tid >> 6;
  int g = l >> 4, c = l & 15;
  int rbase = blockIdx.x * 64 + w * 16;
  int rc = min(rbase + c, N - 1);
  const s16x8* xr = (const s16x8*)(h2b + (size_t)rc * DIM);
  s16x8 A[4];
#pragma unroll
  for (int kt = 0; kt < 4; ++kt) A[kt] = xr[kt * 4 + g];

  const s16x8* Bh = (const s16x8*)mh;
  const s16x8* Bl = (const s16x8*)ml;
  float v[4] = {0.f, 0.f, 0.f, 0.f};
#pragma unroll
  for (int ct = 0; ct < 4; ++ct) {
    f32x4 acc = {0.f, 0.f, 0.f, 0.f};
#pragma unroll
    for (int kt = 0; kt < 4; ++kt) {
      s16x8 bh = Bh[(ct * 16 + c) * 16 + kt * 4 + g];
      s16x8 bl = Bl[(ct * 16 + c) * 16 + kt * 4 + g];
      acc = __builtin_amdgcn_mfma_f32_16x16x32_bf16(A[kt], bh, acc, 0, 0, 0);
      acc = __builtin_amdgcn_mfma_f32_16x16x32_bf16(A[kt], bl, acc, 0, 0, 0);
    }
    int col = ct * 16 + c;
    float b = bm1[col], w2 = wm2[col];
#pragma unroll
    for (int r = 0; r < 4; ++r) v[r] += lrelu(acc[r] + b, 0.01f) * w2;
  }
#pragma unroll
  for (int r = 0; r < 4; ++r) {
    v[r] += __shfl_xor(v[r], 1, 64);
    v[r] += __shfl_xor(v[r], 2, 64);
    v[r] += __shfl_xor(v[r], 4, 64);
    v[r] += __shfl_xor(v[r], 8, 64);
  }
  float b2 = bm2[0];
  float e[4];
#pragma unroll
  for (int r = 0; r < 4; ++r) {
    int rr = rbase + g * 4 + r;
    e[r] = (rr < N) ? __expf(v[r] + b2) : 0.f;
  }
  if (c == 0) {
#pragma unroll
    for (int r = 0; r < 4; ++r) se[w][g * 4 + r] = e[r];
  }
  __syncthreads();
  float emy = se[w][c];   // e for this lane's row (rbase+c)
  float pa[32];
#pragma unroll
  for (int kt = 0; kt < 4; ++kt)
#pragma unroll
    for (int j = 0; j < 8; ++j)
      pa[kt * 8 + j] = emy * bf2f((unsigned short)A[kt][j]);
#pragma unroll
  for (int k = 0; k < 32; ++k) {
    pa[k] += __shfl_xor(pa[k], 1, 64);
    pa[k] += __shfl_xor(pa[k], 2, 64);
    pa[k] += __shfl_xor(pa[k], 4, 64);
    pa[k] += __shfl_xor(pa[k], 8, 64);
  }
  if (c == 0) {
#pragma unroll
    for (int kt = 0; kt < 4; ++kt)
#pragma unroll
      for (int j = 0; j < 8; ++j)
        blkacc[w][kt * 32 + g * 8 + j] = pa[kt * 8 + j];
  }
  float ws = e[0] + e[1] + e[2] + e[3];
  ws += __shfl_xor(ws, 16, 64);
  ws += __shfl_xor(ws, 32, 64);
  if (l == 0) swave[w] = ws;
  __syncthreads();
  if (tid < 128) {
    float s = blkacc[0][tid] + blkacc[1][tid] + blkacc[2][tid] + blkacc[3][tid];
    pagg[(size_t)blockIdx.x * DIM + tid] = s;
  }
  if (tid == 0) psum[blockIdx.x] = swave[0] + swave[1] + swave[2] + swave[3];
}

// ---------------- final: parallel partial-reduce + MLP + layernorm (1024 threads) ----------------
__global__ __launch_bounds__(1024) void k_final(const float* __restrict__ psum, const float* __restrict__ pagg,
                                                int nb,
                                                const float* __restrict__ wa1, const float* __restrict__ ba1,
                                                const float* __restrict__ wa2, const float* __restrict__ ba2,
                                                const float* __restrict__ gamma, const float* __restrict__ beta,
                                                float* __restrict__ out) {
  __shared__ float redz[1024];
  __shared__ float reda[8][128];
  __shared__ float sa[128], shh[64], red[128];
  int t = threadIdx.x;
  float zp = 0.f;
  for (int b = t; b < nb; b += 1024) zp += psum[b];
  redz[t] = zp;
  __syncthreads();
  for (int st = 512; st > 0; st >>= 1) { if (t < st) redz[t] += redz[t + st]; __syncthreads(); }
  int d = t & 127, g = t >> 7;
  float ag = 0.f;
  for (int b = g; b < nb; b += 8) ag += pagg[(size_t)b * DIM + d];
  reda[g][d] = ag;
  __syncthreads();
  if (g == 0) {
    float s = 0.f;
#pragma unroll
    for (int k = 0; k < 8; ++k) s += reda[k][d];
    sa[d] = s / redz[0];
  }
  __syncthreads();
  if (t < 64) {
    float a = 0.f;
    for (int k = 0; k < 128; ++k) a = fmaf(sa[k], wa1[k * 64 + t], a);
    a += ba1[t];
    shh[t] = lrelu(a, 0.01f);
  }
  __syncthreads();
  float zval = 0.f;
  if (t < 128) {
    zval = ba2[t];
    for (int j = 0; j < 64; ++j) zval = fmaf(shh[j], wa2[j * 128 + t], zval);
    red[t] = zval;
  }
  __syncthreads();
  for (int st = 64; st > 0; st >>= 1) { if (t < st) red[t] += red[t + st]; __syncthreads(); }
  float mu = red[0] / 128.f;
  __syncthreads();
  if (t < 128) red[t] = (zval - mu) * (zval - mu);
  __syncthreads();
  for (int st = 64; st > 0; st >>= 1) { if (t < st) red[t] += red[t + st]; __syncthreads(); }
  float var = red[0] / 128.f;
  if (t < 128) out[t] = gamma[t] * (zval - mu) / sqrtf(var + 1e-5f) + beta[t];
}

extern "C" void kernel_launch(void* const* d_in, const int* in_sizes, int n_in,
                              void* d_out, int out_size, void* d_ws, size_t ws_size,
                              hipStream_t stream) {
  const float* feat = (const float*)d_in[0];
  const int* ei = (const int*)d_in[1];
  const float* W1 = (const float*)d_in[2];
  const float* as1 = (const float*)d_in[3];
  const float* ad1 = (const float*)d_in[4];
  const float* b1 = (const float*)d_in[5];
  const float* W2 = (const float*)d_in[6];
  const float* as2 = (const float*)d_in[7];
  const float* ad2 = (const float*)d_in[8];
  const float* b2 = (const float*)d_in[9];
  const float* wm1 = (const float*)d_in[10];
  const float* bm1 = (const float*)d_in[11];
  const float* wm2 = (const float*)d_in[12];
  const float* bm2 = (const float*)d_in[13];
  const float* wa1 = (const float*)d_in[14];
  const float* ba1 = (const float*)d_in[15];
  const float* wa2 = (const float*)d_in[16];
  const float* ba2 = (const float*)d_in[17];
  const float* gamma = (const float*)d_in[18];
  const float* beta = (const float*)d_in[19];
  float* out = (float*)d_out;

  int N = in_sizes[0] / DIM;   // 50000
  int E = in_sizes[1] / 2;     // 600000
  int NB = (N + 255) / 256;
  int ZB = (N + 2047) / 2048;
  int GL = (N + 63) / 64;      // linear blocks (64 rows each)
  int GS = 448;                // scatter blocks in fused kernel
  int gs = (N + 63) / 64;      // score_pool blocks
  int ga = (N + 3) / 4;        // gat blocks (full-row per wave)

  char* ws = (char*)d_ws;
  size_t off = 0;
  auto alloc = [&](size_t bytes) -> void* {
    void* p = ws + off;
    off = (off + bytes + 255) & ~(size_t)255;
    return p;
  };
  int* cnt = (int*)alloc((size_t)N * 4);
  int* rowptr = (int*)alloc((size_t)(N + 1) * 4);
  int* cursor = (int*)alloc((size_t)N * 4);
  int* colb = (int*)alloc((size_t)(E + N) * 4);
  unsigned short* xhb = (unsigned short*)alloc((size_t)N * DIM * 2);
  unsigned short* h1b = (unsigned short*)alloc((size_t)N * DIM * 2);
  unsigned short* h2b = (unsigned short*)alloc((size_t)N * DIM * 2);
  float* asrcb = (float*)alloc((size_t)N * HEADS * 4);
  float* adstb = (float*)alloc((size_t)N * HEADS * 4);
  float* pagg = (float*)alloc((size_t)gs * DIM * 4);
  float* psum = (float*)alloc((size_t)gs * 4);
  int* bsum = (int*)alloc((size_t)NB * 4);
  int* boff = (int*)alloc((size_t)NB * 4);
  unsigned short* wh1 = (unsigned short*)alloc(DIM * DIM * 2);
  unsigned short* sh1 = (unsigned short*)alloc(16 * DIM * 2);
  unsigned short* sl1 = (unsigned short*)alloc(16 * DIM * 2);
  unsigned short* wh2 = (unsigned short*)alloc(DIM * DIM * 2);
  unsigned short* sh2 = (unsigned short*)alloc(16 * DIM * 2);
  unsigned short* sl2 = (unsigned short*)alloc(16 * DIM * 2);
  unsigned short* mh = (unsigned short*)alloc(64 * DIM * 2);
  unsigned short* ml = (unsigned short*)alloc(64 * DIM * 2);

  k_prep<<<44 + ZB, 256, 0, stream>>>(W1, as1, ad1, W2, as2, ad2, wm1,
                                      wh1, sh1, sl1, wh2, sh2, sl2, mh, ml, cnt, N);

  k_hist<<<1024, 256, 0, stream>>>(ei, E, N, cnt);
  k_scan_blk<<<NB, 256, 0, stream>>>(cnt, N, cursor, bsum);
  k_scan_top<<<1, 256, 0, stream>>>(bsum, NB, boff, rowptr + N);
  k_scan_fix<<<NB, 256, 0, stream>>>(cursor, boff, N, rowptr);

  // fused: layer-1 linear (blocks < GL) + CSR edge scatter (blocks >= GL)
  k_linear_mfma<0, 1><<<GL + GS, 256, 0, stream>>>(feat, wh1, sh1, sl1, xhb, asrcb, adstb,
                                                   N, GL, ei, E, cursor, colb);

  k_gat_agg<<<ga, 256, 0, stream>>>(rowptr, colb, xhb, asrcb, adstb, b1, h1b, N);
  k_linear_mfma<1, 0><<<GL, 256, 0, stream>>>(h1b, wh2, sh2, sl2, xhb, asrcb, adstb,
                                              N, GL, nullptr, 0, nullptr, nullptr);
  k_gat_agg<<<ga, 256, 0, stream>>>(rowptr, colb, xhb, asrcb, adstb, b2, h2b, N);

  k_score_pool<<<gs, 256, 0, stream>>>(h2b, mh, ml, bm1, wm2, bm2, pagg, psum, N);
  k_final<<<1, 1024, 0, stream>>>(psum, pagg, gs, wa1, ba1, wa2, ba2, gamma, beta, out);
}

// Round 19
// 222.494 us; speedup vs baseline: 2.0464x; 1.0302x over previous
//
#include <hip/hip_runtime.h>
#include <math.h>

#define DIM 128
#define HEADS 8
#define HD 16
#define CAP 64

typedef __attribute__((ext_vector_type(8))) short s16x8;
typedef __attribute__((ext_vector_type(8))) unsigned short u16x8;
typedef __attribute__((ext_vector_type(4))) float f32x4;

__device__ __forceinline__ float lrelu(float x, float s) { return x >= 0.f ? x : s * x; }

__device__ __forceinline__ unsigned short f2bf(float x) {
  unsigned u = __float_as_uint(x);
  return (unsigned short)((u + 0x7FFFu + ((u >> 16) & 1u)) >> 16);
}
__device__ __forceinline__ float bf2f(unsigned short b) {
  return __uint_as_float(((unsigned)b) << 16);
}

// ---------------- CSR scan kernels ----------------
__global__ __launch_bounds__(256) void k_scan_blk(const int* __restrict__ cnt, int n,
                                                  int* __restrict__ excl, int* __restrict__ bsum) {
  __shared__ int wsum[4];
  int tid = threadIdx.x, l = tid & 63, w = tid >> 6;
  int i = blockIdx.x * 256 + tid;
  int v = (i < n) ? cnt[i] : 0;
  int s = v;
#pragma unroll
  for (int off = 1; off < 64; off <<= 1) {
    int t = __shfl_up(s, off, 64);
    if (l >= off) s += t;
  }
  if (l == 63) wsum[w] = s;
  __syncthreads();
  int add = 0;
#pragma unroll
  for (int k = 0; k < 4; ++k) add += (k < w) ? wsum[k] : 0;
  if (i < n) excl[i] = s + add - v;
  if (tid == 255) bsum[blockIdx.x] = s + add;
}

__global__ __launch_bounds__(256) void k_scan_top(const int* __restrict__ bsum, int nb,
                                                  int* __restrict__ boff, int* __restrict__ rowptrN) {
  __shared__ int wsum[4];
  int tid = threadIdx.x, l = tid & 63, w = tid >> 6;
  int v = (tid < nb) ? bsum[tid] : 0;
  int s = v;
#pragma unroll
  for (int off = 1; off < 64; off <<= 1) {
    int t = __shfl_up(s, off, 64);
    if (l >= off) s += t;
  }
  if (l == 63) wsum[w] = s;
  __syncthreads();
  int add = 0;
#pragma unroll
  for (int k = 0; k < 4; ++k) add += (k < w) ? wsum[k] : 0;
  if (tid < nb) boff[tid] = s + add - v;
  if (tid == 255) *rowptrN = s + add;
}

__global__ __launch_bounds__(256) void k_scan_fix(int* __restrict__ cursor, const int* __restrict__ boff,
                                                  int n, int* __restrict__ rowptr) {
  int i = blockIdx.x * 256 + threadIdx.x;
  if (i < n) {
    int r = boff[blockIdx.x] + cursor[i];
    rowptr[i] = r;
    cursor[i] = r;
  }
}

__global__ void k_scatter(const int* __restrict__ ei, int E, int N,
                          int* __restrict__ cursor, int* __restrict__ colb) {
  int tot = E + N;
  for (int i = blockIdx.x * blockDim.x + threadIdx.x; i < tot; i += gridDim.x * blockDim.x) {
    int s, d;
    if (i < E) { s = ei[i]; d = ei[E + i]; } else { s = i - E; d = s; }
    int pos = atomicAdd(&cursor[d], 1);
    colb[pos] = s;
  }
}

// ---------------- unified weight prep + cnt zeroing ----------------
__global__ __launch_bounds__(256) void k_prep(
    const float* __restrict__ W1, const float* __restrict__ as1, const float* __restrict__ ad1,
    const float* __restrict__ W2, const float* __restrict__ as2, const float* __restrict__ ad2,
    const float* __restrict__ wm1,
    unsigned short* __restrict__ wh1,
    unsigned short* __restrict__ sh1, unsigned short* __restrict__ sl1,
    unsigned short* __restrict__ wh2,
    unsigned short* __restrict__ sh2, unsigned short* __restrict__ sl2,
    unsigned short* __restrict__ mh, unsigned short* __restrict__ ml,
    int* __restrict__ cnt, int N) {
  int b = blockIdx.x, tid = threadIdx.x;
  if (b < 32) {
    int layer = b >> 4;
    const float* W = layer ? W2 : W1;
    unsigned short* wh = layer ? wh2 : wh1;
    int lo = (b & 15) * 1024;
    for (int idx = lo + tid; idx < lo + 1024; idx += 256) {
      int n = idx >> 7, k = idx & 127;
      wh[idx] = f2bf(W[k * DIM + n]);
    }
  } else if (b < 36) {
    int layer = (b - 32) >> 1;
    const float* W = layer ? W2 : W1;
    const float* avs = layer ? as2 : as1;
    const float* avd = layer ? ad2 : ad1;
    unsigned short* sh = layer ? sh2 : sh1;
    unsigned short* sl = layer ? sl2 : sl1;
    int lo = ((b - 32) & 1) * 1024;
    for (int idx = lo + tid; idx < lo + 1024; idx += 256) {
      int n = idx >> 7, k = idx & 127;
      float acc = 0.f;
      if (n < 8) {
#pragma unroll
        for (int j = 0; j < 16; ++j) acc += W[k * DIM + n * 16 + j] * avs[n * 16 + j];
      } else {
        int h = n - 8;
#pragma unroll
        for (int j = 0; j < 16; ++j) acc += W[k * DIM + h * 16 + j] * avd[h * 16 + j];
      }
      unsigned short hb = f2bf(acc);
      sh[idx] = hb;
      sl[idx] = f2bf(acc - bf2f(hb));
    }
  } else if (b < 44) {
    int lo = (b - 36) * 1024;
    for (int idx = lo + tid; idx < lo + 1024; idx += 256) {
      int j = idx >> 7, k = idx & 127;   // mh[j][k] = wm1[k][j]
      float v = wm1[k * 64 + j];
      unsigned short hb = f2bf(v);
      mh[idx] = hb;
      ml[idx] = f2bf(v - bf2f(hb));
    }
  } else {
    int i0 = (b - 44) * 2048 + tid * 8;
    if (i0 + 8 <= N) {
      int4 z = {0, 0, 0, 0};
      *(int4*)(cnt + i0) = z;
      *(int4*)(cnt + i0 + 4) = z;
    } else {
      for (int i = i0; i < N; ++i) cnt[i] = 0;
    }
  }
}

// ---------------- linear v3: W staged in LDS (coalesced, once/block); wave = 16-row tile x 128 cols
template <int BF16IN, int FUSEHIST>
__global__ __launch_bounds__(256) void k_linear_mfma(
    const void* __restrict__ xin,
    const unsigned short* __restrict__ wh,
    const unsigned short* __restrict__ sh, const unsigned short* __restrict__ sl,
    unsigned short* __restrict__ xhb, float* __restrict__ asrc, float* __restrict__ adst,
    int N, int GL,
    const int* __restrict__ ei, int E, int* __restrict__ cnt) {
  if constexpr (FUSEHIST) {
    if ((int)blockIdx.x >= GL) {
      int tot = E + N;
      int nhb = gridDim.x - GL;
      for (int i = ((int)blockIdx.x - GL) * 256 + (int)threadIdx.x; i < tot; i += nhb * 256) {
        int d = (i < E) ? ei[E + i] : (i - E);  // self-loops appended
        atomicAdd(&cnt[d], 1);
      }
      return;
    }
  }
  __shared__ unsigned short sB[160][136];
  __shared__ unsigned short otile[64][136];
  __shared__ float atile[64][16];
  int tid = threadIdx.x, l = tid & 63, w = tid >> 6;
  int g = l >> 4, c = l & 15;
  int rb = blockIdx.x * 64;

  // stage W + alpha cols into LDS (coalesced u16x8 loads; source is L2-resident)
  for (int i = tid; i < 160 * 16; i += 256) {
    int row = i >> 4, c8 = i & 15;
    u16x8 v;
    if (row < 128) v = *(const u16x8*)(wh + row * 128 + c8 * 8);
    else if (row < 144) v = *(const u16x8*)(sh + (row - 128) * 128 + c8 * 8);
    else v = *(const u16x8*)(sl + (row - 144) * 128 + c8 * 8);
    *(u16x8*)&sB[row][c8 * 8] = v;
  }

  // A loads: wave w owns rows rb + w*16 + [0,16)
  int rc = min(rb + w * 16 + c, N - 1);
  s16x8 A[4];
  if constexpr (BF16IN) {
    const s16x8* xr = (const s16x8*)((const unsigned short*)xin + (size_t)rc * DIM);
#pragma unroll
    for (int kt = 0; kt < 4; ++kt) A[kt] = xr[kt * 4 + g];
  } else {
    const float4* xf = (const float4*)((const float*)xin + (size_t)rc * DIM);
#pragma unroll
    for (int kt = 0; kt < 4; ++kt) {
      float4 p = xf[kt * 8 + g * 2];
      float4 q = xf[kt * 8 + g * 2 + 1];
      s16x8 a;
      a[0] = (short)f2bf(p.x); a[1] = (short)f2bf(p.y);
      a[2] = (short)f2bf(p.z); a[3] = (short)f2bf(p.w);
      a[4] = (short)f2bf(q.x); a[5] = (short)f2bf(q.y);
      a[6] = (short)f2bf(q.z); a[7] = (short)f2bf(q.w);
      A[kt] = a;
    }
  }
  __syncthreads();

  f32x4 acc[8];
#pragma unroll
  for (int ct = 0; ct < 8; ++ct) acc[ct] = (f32x4){0.f, 0.f, 0.f, 0.f};
#pragma unroll
  for (int kt = 0; kt < 4; ++kt) {
    s16x8 a = A[kt];
#pragma unroll
    for (int ct = 0; ct < 8; ++ct) {
      s16x8 b = *(const s16x8*)&sB[ct * 16 + c][kt * 32 + g * 8];
      acc[ct] = __builtin_amdgcn_mfma_f32_16x16x32_bf16(a, b, acc[ct], 0, 0, 0);
    }
  }
  f32x4 accS = {0.f, 0.f, 0.f, 0.f};
#pragma unroll
  for (int kt = 0; kt < 4; ++kt) {
    s16x8 shi = *(const s16x8*)&sB[128 + c][kt * 32 + g * 8];
    s16x8 slo = *(const s16x8*)&sB[144 + c][kt * 32 + g * 8];
    accS = __builtin_amdgcn_mfma_f32_16x16x32_bf16(A[kt], shi, accS, 0, 0, 0);
    accS = __builtin_amdgcn_mfma_f32_16x16x32_bf16(A[kt], slo, accS, 0, 0, 0);
  }

  // stage outputs (C-fragment layout: col=c, row=g*4+r)
#pragma unroll
  for (int ct = 0; ct < 8; ++ct)
#pragma unroll
    for (int r = 0; r < 4; ++r)
      otile[w * 16 + g * 4 + r][ct * 16 + c] = f2bf(acc[ct][r]);
#pragma unroll
  for (int r = 0; r < 4; ++r) atile[w * 16 + g * 4 + r][c] = accS[r];
  __syncthreads();

  // coalesced write-out
#pragma unroll
  for (int p = 0; p < 4; ++p) {
    int row = p * 16 + (tid >> 4), cb = tid & 15;
    int rr = rb + row;
    if (rr < N) {
      u16x8 v = *(const u16x8*)&otile[row][cb * 8];
      *(u16x8*)(xhb + (size_t)rr * DIM + cb * 8) = v;
      float av = atile[row][cb];
      if (cb < 8) asrc[rr * HEADS + cb] = av;
      else adst[rr * HEADS + (cb - 8)] = av;
    }
  }
}

// ---------------- GAT aggregation: single-pass softmax, bf16 output ----------------
__global__ __launch_bounds__(256) void k_gat_agg(const int* __restrict__ rowptr, const int* __restrict__ colb,
                                                 const unsigned short* __restrict__ xhb,
                                                 const float* __restrict__ asrc, const float* __restrict__ adst,
                                                 const float* __restrict__ bias,
                                                 unsigned short* __restrict__ houtb, int N) {
  __shared__ int ci[4][CAP];
  int tid = threadIdx.x, lane = tid & 63, wv = tid >> 6;
  int n = blockIdx.x * 4 + wv;
  int base = 0, deg = 0;
  if (n < N) { base = rowptr[n]; deg = rowptr[n + 1] - base; }
  if (lane < deg && lane < CAP) ci[wv][lane] = colb[base + lane];
  __syncthreads();
  if (n >= N) return;

  int qt = lane >> 4, q = lane & 15;   // quarter = edge slot parity; lane covers dims [8q, 8q+8)
  int h = q >> 1;
  float adn = adst[n * HEADS + h];
  float den = 0.f;
  float a0 = 0.f, a1 = 0.f, a2 = 0.f, a3 = 0.f, a4 = 0.f, a5 = 0.f, a6 = 0.f, a7 = 0.f;
#define EDGE(ii) { \
    int c_ = ((ii) < CAP) ? ci[wv][(ii)] : colb[base + (ii)]; \
    float e_ = lrelu(asrc[c_ * HEADS + h] + adn, 0.2f); \
    float w_ = __expf(e_); \
    den += w_; \
    u16x8 u_ = *(const u16x8*)(xhb + (size_t)c_ * DIM + q * 8); \
    a0 = fmaf(w_, bf2f((unsigned short)u_[0]), a0); \
    a1 = fmaf(w_, bf2f((unsigned short)u_[1]), a1); \
    a2 = fmaf(w_, bf2f((unsigned short)u_[2]), a2); \
    a3 = fmaf(w_, bf2f((unsigned short)u_[3]), a3); \
    a4 = fmaf(w_, bf2f((unsigned short)u_[4]), a4); \
    a5 = fmaf(w_, bf2f((unsigned short)u_[5]), a5); \
    a6 = fmaf(w_, bf2f((unsigned short)u_[6]), a6); \
    a7 = fmaf(w_, bf2f((unsigned short)u_[7]), a7); }
  int i = qt;
  for (; i + 4 < deg; i += 8) { EDGE(i); EDGE(i + 4); }
  for (; i < deg; i += 4) { EDGE(i); }
#undef EDGE
  den += __shfl_xor(den, 16, 64); den += __shfl_xor(den, 32, 64);
  a0 += __shfl_xor(a0, 16, 64); a0 += __shfl_xor(a0, 32, 64);
  a1 += __shfl_xor(a1, 16, 64); a1 += __shfl_xor(a1, 32, 64);
  a2 += __shfl_xor(a2, 16, 64); a2 += __shfl_xor(a2, 32, 64);
  a3 += __shfl_xor(a3, 16, 64); a3 += __shfl_xor(a3, 32, 64);
  a4 += __shfl_xor(a4, 16, 64); a4 += __shfl_xor(a4, 32, 64);
  a5 += __shfl_xor(a5, 16, 64); a5 += __shfl_xor(a5, 32, 64);
  a6 += __shfl_xor(a6, 16, 64); a6 += __shfl_xor(a6, 32, 64);
  a7 += __shfl_xor(a7, 16, 64); a7 += __shfl_xor(a7, 32, 64);
  if (qt == 0) {
    float r = 1.f / (den + 1e-16f);
    const float4* bp = (const float4*)(bias + q * 8);
    float4 b0 = bp[0], b1 = bp[1];
    u16x8 o;
    o[0] = f2bf(lrelu(fmaf(a0, r, b0.x), 0.01f));
    o[1] = f2bf(lrelu(fmaf(a1, r, b0.y), 0.01f));
    o[2] = f2bf(lrelu(fmaf(a2, r, b0.z), 0.01f));
    o[3] = f2bf(lrelu(fmaf(a3, r, b0.w), 0.01f));
    o[4] = f2bf(lrelu(fmaf(a4, r, b1.x), 0.01f));
    o[5] = f2bf(lrelu(fmaf(a5, r, b1.y), 0.01f));
    o[6] = f2bf(lrelu(fmaf(a6, r, b1.z), 0.01f));
    o[7] = f2bf(lrelu(fmaf(a7, r, b1.w), 0.01f));
    *(u16x8*)(houtb + (size_t)n * DIM + q * 8) = o;
  }
}

// ---------------- fused score MLP + softmax pooling: per-block partials ----------------
__global__ __launch_bounds__(256) void k_score_pool(
    const unsigned short* __restrict__ h2b,
    const unsigned short* __restrict__ mh, const unsigned short* __restrict__ ml,
    const float* __restrict__ bm1, const float* __restrict__ wm2, const float* __restrict__ bm2,
    float* __restrict__ pagg, float* __restrict__ psum, int N) {
  __shared__ float se[4][16];
  __shared__ float blkacc[4][128];
  __shared__ float swave[4];
  int tid = threadIdx.x, l = tid & 63, w = tid >> 6;
  int g = l >> 4, c = l & 15;
  int rbase = blockIdx.x * 64 + w * 16;
  int rc = min(rbase + c, N - 1);
  const s16x8* xr = (const s16x8*)(h2b + (size_t)rc * DIM);
  s16x8 A[4];
#pragma unroll
  for (int kt = 0; kt < 4; ++kt) A[kt] = xr[kt * 4 + g];

  const s16x8* Bh = (const s16x8*)mh;
  const s16x8* Bl = (const s16x8*)ml;
  float v[4] = {0.f, 0.f, 0.f, 0.f};
#pragma unroll
  for (int ct = 0; ct < 4; ++ct) {
    f32x4 acc = {0.f, 0.f, 0.f, 0.f};
#pragma unroll
    for (int kt = 0; kt < 4; ++kt) {
      s16x8 bh = Bh[(ct * 16 + c) * 16 + kt * 4 + g];
      s16x8 bl = Bl[(ct * 16 + c) * 16 + kt * 4 + g];
      acc = __builtin_amdgcn_mfma_f32_16x16x32_bf16(A[kt], bh, acc, 0, 0, 0);
      acc = __builtin_amdgcn_mfma_f32_16x16x32_bf16(A[kt], bl, acc, 0, 0, 0);
    }
    int col = ct * 16 + c;
    float b = bm1[col], w2 = wm2[col];
#pragma unroll
    for (int r = 0; r < 4; ++r) v[r] += lrelu(acc[r] + b, 0.01f) * w2;
  }
#pragma unroll
  for (int r = 0; r < 4; ++r) {
    v[r] += __shfl_xor(v[r], 1, 64);
    v[r] += __shfl_xor(v[r], 2, 64);
    v[r] += __shfl_xor(v[r], 4, 64);
    v[r] += __shfl_xor(v[r], 8, 64);
  }
  float b2 = bm2[0];
  float e[4];
#pragma unroll
  for (int r = 0; r < 4; ++r) {
    int rr = rbase + g * 4 + r;
    e[r] = (rr < N) ? __expf(v[r] + b2) : 0.f;
  }
  if (c == 0) {
#pragma unroll
    for (int r = 0; r < 4; ++r) se[w][g * 4 + r] = e[r];
  }
  __syncthreads();
  float emy = se[w][c];   // e for this lane's row (rbase+c)
  float pa[32];
#pragma unroll
  for (int kt = 0; kt < 4; ++kt)
#pragma unroll
    for (int j = 0; j < 8; ++j)
      pa[kt * 8 + j] = emy * bf2f((unsigned short)A[kt][j]);
#pragma unroll
  for (int k = 0; k < 32; ++k) {
    pa[k] += __shfl_xor(pa[k], 1, 64);
    pa[k] += __shfl_xor(pa[k], 2, 64);
    pa[k] += __shfl_xor(pa[k], 4, 64);
    pa[k] += __shfl_xor(pa[k], 8, 64);
  }
  if (c == 0) {
#pragma unroll
    for (int kt = 0; kt < 4; ++kt)
#pragma unroll
      for (int j = 0; j < 8; ++j)
        blkacc[w][kt * 32 + g * 8 + j] = pa[kt * 8 + j];
  }
  float ws = e[0] + e[1] + e[2] + e[3];
  ws += __shfl_xor(ws, 16, 64);
  ws += __shfl_xor(ws, 32, 64);
  if (l == 0) swave[w] = ws;
  __syncthreads();
  if (tid < 128) {
    float s = blkacc[0][tid] + blkacc[1][tid] + blkacc[2][tid] + blkacc[3][tid];
    pagg[(size_t)blockIdx.x * DIM + tid] = s;
  }
  if (tid == 0) psum[blockIdx.x] = swave[0] + swave[1] + swave[2] + swave[3];
}

// ---------------- final: parallel partial-reduce + MLP + layernorm (1024 threads) ----------------
__global__ __launch_bounds__(1024) void k_final(const float* __restrict__ psum, const float* __restrict__ pagg,
                                                int nb,
                                                const float* __restrict__ wa1, const float* __restrict__ ba1,
                                                const float* __restrict__ wa2, const float* __restrict__ ba2,
                                                const float* __restrict__ gamma, const float* __restrict__ beta,
                                                float* __restrict__ out) {
  __shared__ float redz[1024];
  __shared__ float reda[8][128];
  __shared__ float sa[128], shh[64], red[128];
  int t = threadIdx.x;
  float zp = 0.f;
  for (int b = t; b < nb; b += 1024) zp += psum[b];
  redz[t] = zp;
  __syncthreads();
  for (int st = 512; st > 0; st >>= 1) { if (t < st) redz[t] += redz[t + st]; __syncthreads(); }
  int d = t & 127, g = t >> 7;
  float ag = 0.f;
  for (int b = g; b < nb; b += 8) ag += pagg[(size_t)b * DIM + d];
  reda[g][d] = ag;
  __syncthreads();
  if (g == 0) {
    float s = 0.f;
#pragma unroll
    for (int k = 0; k < 8; ++k) s += reda[k][d];
    sa[d] = s / redz[0];
  }
  __syncthreads();
  if (t < 64) {
    float a = 0.f;
    for (int k = 0; k < 128; ++k) a = fmaf(sa[k], wa1[k * 64 + t], a);
    a += ba1[t];
    shh[t] = lrelu(a, 0.01f);
  }
  __syncthreads();
  float zval = 0.f;
  if (t < 128) {
    zval = ba2[t];
    for (int j = 0; j < 64; ++j) zval = fmaf(shh[j], wa2[j * 128 + t], zval);
    red[t] = zval;
  }
  __syncthreads();
  for (int st = 64; st > 0; st >>= 1) { if (t < st) red[t] += red[t + st]; __syncthreads(); }
  float mu = red[0] / 128.f;
  __syncthreads();
  if (t < 128) red[t] = (zval - mu) * (zval - mu);
  __syncthreads();
  for (int st = 64; st > 0; st >>= 1) { if (t < st) red[t] += red[t + st]; __syncthreads(); }
  float var = red[0] / 128.f;
  if (t < 128) out[t] = gamma[t] * (zval - mu) / sqrtf(var + 1e-5f) + beta[t];
}

extern "C" void kernel_launch(void* const* d_in, const int* in_sizes, int n_in,
                              void* d_out, int out_size, void* d_ws, size_t ws_size,
                              hipStream_t stream) {
  const float* feat = (const float*)d_in[0];
  const int* ei = (const int*)d_in[1];
  const float* W1 = (const float*)d_in[2];
  const float* as1 = (const float*)d_in[3];
  const float* ad1 = (const float*)d_in[4];
  const float* b1 = (const float*)d_in[5];
  const float* W2 = (const float*)d_in[6];
  const float* as2 = (const float*)d_in[7];
  const float* ad2 = (const float*)d_in[8];
  const float* b2 = (const float*)d_in[9];
  const float* wm1 = (const float*)d_in[10];
  const float* bm1 = (const float*)d_in[11];
  const float* wm2 = (const float*)d_in[12];
  const float* bm2 = (const float*)d_in[13];
  const float* wa1 = (const float*)d_in[14];
  const float* ba1 = (const float*)d_in[15];
  const float* wa2 = (const float*)d_in[16];
  const float* ba2 = (const float*)d_in[17];
  const float* gamma = (const float*)d_in[18];
  const float* beta = (const float*)d_in[19];
  float* out = (float*)d_out;

  int N = in_sizes[0] / DIM;   // 50000
  int E = in_sizes[1] / 2;     // 600000
  int NB = (N + 255) / 256;
  int ZB = (N + 2047) / 2048;
  int GL = (N + 63) / 64;      // linear blocks (64 rows each)
  int GH = 448;                // hist blocks in fused front kernel
  int gs = (N + 63) / 64;      // score_pool blocks

  char* ws = (char*)d_ws;
  size_t off = 0;
  auto alloc = [&](size_t bytes) -> void* {
    void* p = ws + off;
    off = (off + bytes + 255) & ~(size_t)255;
    return p;
  };
  int* cnt = (int*)alloc((size_t)N * 4);
  int* rowptr = (int*)alloc((size_t)(N + 1) * 4);
  int* cursor = (int*)alloc((size_t)N * 4);
  int* colb = (int*)alloc((size_t)(E + N) * 4);
  unsigned short* xhb = (unsigned short*)alloc((size_t)N * DIM * 2);
  unsigned short* h1b = (unsigned short*)alloc((size_t)N * DIM * 2);
  unsigned short* h2b = (unsigned short*)alloc((size_t)N * DIM * 2);
  float* asrcb = (float*)alloc((size_t)N * HEADS * 4);
  float* adstb = (float*)alloc((size_t)N * HEADS * 4);
  float* pagg = (float*)alloc((size_t)gs * DIM * 4);
  float* psum = (float*)alloc((size_t)gs * 4);
  int* bsum = (int*)alloc((size_t)NB * 4);
  int* boff = (int*)alloc((size_t)NB * 4);
  unsigned short* wh1 = (unsigned short*)alloc(DIM * DIM * 2);
  unsigned short* sh1 = (unsigned short*)alloc(16 * DIM * 2);
  unsigned short* sl1 = (unsigned short*)alloc(16 * DIM * 2);
  unsigned short* wh2 = (unsigned short*)alloc(DIM * DIM * 2);
  unsigned short* sh2 = (unsigned short*)alloc(16 * DIM * 2);
  unsigned short* sl2 = (unsigned short*)alloc(16 * DIM * 2);
  unsigned short* mh = (unsigned short*)alloc(64 * DIM * 2);
  unsigned short* ml = (unsigned short*)alloc(64 * DIM * 2);

  k_prep<<<44 + ZB, 256, 0, stream>>>(W1, as1, ad1, W2, as2, ad2, wm1,
                                      wh1, sh1, sl1, wh2, sh2, sl2, mh, ml, cnt, N);

  // fused: layer-1 linear (blocks < GL) + edge histogram (blocks >= GL)
  k_linear_mfma<0, 1><<<GL + GH, 256, 0, stream>>>(feat, wh1, sh1, sl1, xhb, asrcb, adstb,
                                                   N, GL, ei, E, cnt);

  k_scan_blk<<<NB, 256, 0, stream>>>(cnt, N, cursor, bsum);
  k_scan_top<<<1, 256, 0, stream>>>(bsum, NB, boff, rowptr + N);
  k_scan_fix<<<NB, 256, 0, stream>>>(cursor, boff, N, rowptr);
  k_scatter<<<1024, 256, 0, stream>>>(ei, E, N, cursor, colb);

  int ga = (N + 3) / 4;
  k_gat_agg<<<ga, 256, 0, stream>>>(rowptr, colb, xhb, asrcb, adstb, b1, h1b, N);
  k_linear_mfma<1, 0><<<GL, 256, 0, stream>>>(h1b, wh2, sh2, sl2, xhb, asrcb, adstb,
                                              N, GL, nullptr, 0, nullptr);
  k_gat_agg<<<ga, 256, 0, stream>>>(rowptr, colb, xhb, asrcb, adstb, b2, h2b, N);

  k_score_pool<<<gs, 256, 0, stream>>>(h2b, mh, ml, bm1, wm2, bm2, pagg, psum, N);
  k_final<<<1, 1024, 0, stream>>>(psum, pagg, gs, wa1, ba1, wa2, ba2, gamma, beta, out);
}